// Round 1
// baseline (576.793 us; speedup 1.0000x reference)
//
#include <hip/hip_runtime.h>

#define NNODE 50000
#define NEDGE 800000
#define NBN   1563   // ceil(50000/32) node blocks in prep

// workspace layout (float offsets)
#define WS_QC   0                      // 64*64
#define WS_WR2  4096                   // 64*64   Wr' = Wr @ W1[128:192]
#define WS_B1P  8192                   // 64      b1' = b1 + br @ W1[128:192]
#define WS_NH   8256                   // 50000*64
#define WS_NT   (8256 + NNODE * 64)    // 50000*64

__global__ __launch_bounds__(256)
void prep_kernel(const float* __restrict__ Q,
                 const float* __restrict__ Xn,
                 const float* __restrict__ Wq, const float* __restrict__ bq,
                 const float* __restrict__ We, const float* __restrict__ be,
                 const float* __restrict__ Wr, const float* __restrict__ br,
                 const float* __restrict__ W1, const float* __restrict__ b1,
                 float* __restrict__ ws)
{
    __shared__ float smem[8192];
    const int t = threadIdx.x;
    const int bid = blockIdx.x;

    if (bid < NBN) {
        // ---- node blocks: nh/nt tables, 32 nodes per block ----
        float* sW = smem;           // 4096
        float* sX = smem + 4096;    // 2048
        float* sR = smem + 6144;    // 2048
        const int nbase = bid * 32;

        #pragma unroll
        for (int i = 0; i < 2; ++i) {
            int f = t + i * 256;
            int n = f >> 4, s4 = (f & 15) * 4;
            int gn = nbase + n;
            float4 v = make_float4(0.f, 0.f, 0.f, 0.f);
            if (gn < NNODE) v = *(const float4*)&Xn[gn * 64 + s4];
            *(float4*)&sX[n * 64 + s4] = v;
        }
        #pragma unroll
        for (int i = 0; i < 4; ++i) {
            int f = t + i * 256;
            *(float4*)&sW[f * 4] = *(const float4*)&We[f * 4];
        }
        __syncthreads();

        const int n0 = (t >> 4) * 2;
        const int m0 = (t & 15) * 4;

        // node_repr = Xn @ We + be
        float r0[4], r1[4];
        #pragma unroll
        for (int i = 0; i < 4; ++i) { r0[i] = be[m0 + i]; r1[i] = be[m0 + i]; }
        #pragma unroll 8
        for (int d = 0; d < 64; ++d) {
            float x0 = sX[n0 * 64 + d];
            float x1 = sX[n0 * 64 + 64 + d];
            float4 b = *(const float4*)&sW[d * 64 + m0];
            r0[0] = fmaf(x0, b.x, r0[0]); r0[1] = fmaf(x0, b.y, r0[1]);
            r0[2] = fmaf(x0, b.z, r0[2]); r0[3] = fmaf(x0, b.w, r0[3]);
            r1[0] = fmaf(x1, b.x, r1[0]); r1[1] = fmaf(x1, b.y, r1[1]);
            r1[2] = fmaf(x1, b.z, r1[2]); r1[3] = fmaf(x1, b.w, r1[3]);
        }
        *(float4*)&sR[n0 * 64 + m0]      = make_float4(r0[0], r0[1], r0[2], r0[3]);
        *(float4*)&sR[n0 * 64 + 64 + m0] = make_float4(r1[0], r1[1], r1[2], r1[3]);
        __syncthreads();

        // two passes: W1 rows 64..127 -> nh, rows 192..255 -> nt
        #pragma unroll
        for (int pass = 0; pass < 2; ++pass) {
            const float* w1seg = W1 + (pass == 0 ? 64 * 64 : 192 * 64);
            #pragma unroll
            for (int i = 0; i < 4; ++i) {
                int f = t + i * 256;
                *(float4*)&sW[f * 4] = *(const float4*)&w1seg[f * 4];
            }
            __syncthreads();
            float a0[4] = {0.f, 0.f, 0.f, 0.f}, a1[4] = {0.f, 0.f, 0.f, 0.f};
            #pragma unroll 8
            for (int k = 0; k < 64; ++k) {
                float x0 = sR[n0 * 64 + k];
                float x1 = sR[n0 * 64 + 64 + k];
                float4 b = *(const float4*)&sW[k * 64 + m0];
                a0[0] = fmaf(x0, b.x, a0[0]); a0[1] = fmaf(x0, b.y, a0[1]);
                a0[2] = fmaf(x0, b.z, a0[2]); a0[3] = fmaf(x0, b.w, a0[3]);
                a1[0] = fmaf(x1, b.x, a1[0]); a1[1] = fmaf(x1, b.y, a1[1]);
                a1[2] = fmaf(x1, b.z, a1[2]); a1[3] = fmaf(x1, b.w, a1[3]);
            }
            float* dst = ws + (pass == 0 ? WS_NH : WS_NT);
            if (nbase + n0 < NNODE)
                *(float4*)&dst[(nbase + n0) * 64 + m0] = make_float4(a0[0], a0[1], a0[2], a0[3]);
            if (nbase + n0 + 1 < NNODE)
                *(float4*)&dst[(nbase + n0 + 1) * 64 + m0] = make_float4(a1[0], a1[1], a1[2], a1[3]);
            __syncthreads();
        }
    } else if (bid == NBN) {
        // ---- qc = (Q @ Wq + bq) @ W1[0:64] ----
        float* sA = smem;
        float* sB = smem + 4096;
        #pragma unroll
        for (int i = 0; i < 4; ++i) {
            int f = t + i * 256;
            *(float4*)&sA[f * 4] = *(const float4*)&Q[f * 4];
            *(float4*)&sB[f * 4] = *(const float4*)&Wq[f * 4];
        }
        __syncthreads();
        const int r0 = (t >> 4) * 4, c0 = (t & 15) * 4;
        float acc[4][4];
        #pragma unroll
        for (int j = 0; j < 4; ++j)
            #pragma unroll
            for (int i = 0; i < 4; ++i) acc[j][i] = bq[c0 + i];
        #pragma unroll 4
        for (int d = 0; d < 64; ++d) {
            float4 b = *(const float4*)&sB[d * 64 + c0];
            float bv[4] = {b.x, b.y, b.z, b.w};
            #pragma unroll
            for (int j = 0; j < 4; ++j) {
                float a = sA[(r0 + j) * 64 + d];
                #pragma unroll
                for (int i = 0; i < 4; ++i) acc[j][i] = fmaf(a, bv[i], acc[j][i]);
            }
        }
        __syncthreads();
        #pragma unroll
        for (int j = 0; j < 4; ++j)
            *(float4*)&sA[(r0 + j) * 64 + c0] = make_float4(acc[j][0], acc[j][1], acc[j][2], acc[j][3]);
        __syncthreads();
        #pragma unroll
        for (int i = 0; i < 4; ++i) {
            int f = t + i * 256;
            *(float4*)&sB[f * 4] = *(const float4*)&W1[f * 4];   // rows 0..63
        }
        __syncthreads();
        float qa[4][4];
        #pragma unroll
        for (int j = 0; j < 4; ++j)
            #pragma unroll
            for (int i = 0; i < 4; ++i) qa[j][i] = 0.f;
        #pragma unroll 4
        for (int k = 0; k < 64; ++k) {
            float4 b = *(const float4*)&sB[k * 64 + c0];
            float bv[4] = {b.x, b.y, b.z, b.w};
            #pragma unroll
            for (int j = 0; j < 4; ++j) {
                float a = sA[(r0 + j) * 64 + k];
                #pragma unroll
                for (int i = 0; i < 4; ++i) qa[j][i] = fmaf(a, bv[i], qa[j][i]);
            }
        }
        #pragma unroll
        for (int j = 0; j < 4; ++j)
            *(float4*)&ws[WS_QC + (r0 + j) * 64 + c0] = make_float4(qa[j][0], qa[j][1], qa[j][2], qa[j][3]);
    } else {
        // ---- Wr' = Wr @ W1[128:192]; b1' ----
        float* sA = smem;
        float* sB = smem + 4096;
        #pragma unroll
        for (int i = 0; i < 4; ++i) {
            int f = t + i * 256;
            *(float4*)&sA[f * 4] = *(const float4*)&Wr[f * 4];
            *(float4*)&sB[f * 4] = *(const float4*)&W1[128 * 64 + f * 4];
        }
        __syncthreads();
        const int r0 = (t >> 4) * 4, c0 = (t & 15) * 4;
        float acc[4][4];
        #pragma unroll
        for (int j = 0; j < 4; ++j)
            #pragma unroll
            for (int i = 0; i < 4; ++i) acc[j][i] = 0.f;
        #pragma unroll 4
        for (int m = 0; m < 64; ++m) {
            float4 b = *(const float4*)&sB[m * 64 + c0];
            float bv[4] = {b.x, b.y, b.z, b.w};
            #pragma unroll
            for (int j = 0; j < 4; ++j) {
                float a = sA[(r0 + j) * 64 + m];
                #pragma unroll
                for (int i = 0; i < 4; ++i) acc[j][i] = fmaf(a, bv[i], acc[j][i]);
            }
        }
        #pragma unroll
        for (int j = 0; j < 4; ++j)
            *(float4*)&ws[WS_WR2 + (r0 + j) * 64 + c0] = make_float4(acc[j][0], acc[j][1], acc[j][2], acc[j][3]);
        if (t < 64) {
            float a = b1[t];
            for (int k = 0; k < 64; ++k) a = fmaf(br[k], sB[k * 64 + t], a);
            ws[WS_B1P + t] = a;
        }
    }
}

__global__ __launch_bounds__(256, 3)
void edge_kernel(const float* __restrict__ Xe,
                 const int* __restrict__ EI,
                 const int* __restrict__ NB,
                 const float* __restrict__ W2,
                 const float* __restrict__ b2,
                 const float* __restrict__ Wh,
                 const float* __restrict__ bh,
                 const float* __restrict__ ws,
                 float* __restrict__ out)
{
    __shared__ float sBuf[64 * 68];   // XT (stride 68) then H1T
    __shared__ float sWU[4 * 2052];   // Wr' row-major (4096) then W2 bank-phased panels
    __shared__ float sB1p[64];
    __shared__ float sB2[128];
    __shared__ float sWh[128];
    __shared__ int   sHead[64], sTail[64], sQid[64];

    const int t = threadIdx.x;
    const int ebase = blockIdx.x * 64;

    const float* qc  = ws + WS_QC;
    const float* wr2 = ws + WS_WR2;
    const float* b1p = ws + WS_B1P;
    const float* nhp = ws + WS_NH;
    const float* ntp = ws + WS_NT;

    // preload W2 into registers; store to LDS after h1 (hides the global latency)
    float4 w2r[8];
    #pragma unroll
    for (int i = 0; i < 8; ++i) {
        int f = t + i * 256;
        w2r[i] = *(const float4*)&W2[f * 4];
    }

    if (t < 64) {
        int h  = EI[ebase + t];
        int tl = EI[NEDGE + ebase + t];
        sHead[t] = h;
        sTail[t] = tl;
        sQid[t]  = NB[h];
    } else if (t < 128) {
        sB1p[t - 64] = b1p[t - 64];
        sWh[t - 64]  = Wh[t - 64];
        sWh[t]       = Wh[t];
    } else {
        sB2[t - 128] = b2[t - 128];
    }

    #pragma unroll
    for (int i = 0; i < 4; ++i) {
        int f = t + i * 256;
        *(float4*)&sWU[f * 4] = *(const float4*)&wr2[f * 4];
    }
    // X tile, transposed: sBuf[d][e], row stride 68
    #pragma unroll
    for (int i = 0; i < 4; ++i) {
        int f = t + i * 256;
        int e = f >> 4, s4 = (f & 15) * 4;
        float4 v = *(const float4*)&Xe[(ebase + e) * 64 + s4];
        sBuf[(s4 + 0) * 68 + e] = v.x;
        sBuf[(s4 + 1) * 68 + e] = v.y;
        sBuf[(s4 + 2) * 68 + e] = v.z;
        sBuf[(s4 + 3) * 68 + e] = v.w;
    }
    __syncthreads();

    const int er = (t >> 4) * 4;   // 4 edges per thread
    const int cc = (t & 15) * 4;   // 4 h1 cols per thread

    // ---- h1 = relu(X @ Wr' + qc[qid] + nh[head] + nt[tail] + b1') ----
    float acc[4][4];
    #pragma unroll
    for (int j = 0; j < 4; ++j)
        #pragma unroll
        for (int i = 0; i < 4; ++i) acc[j][i] = 0.f;

    #pragma unroll 4
    for (int k = 0; k < 64; ++k) {
        float4 a = *(const float4*)&sBuf[k * 68 + er];
        float4 b = *(const float4*)&sWU[k * 64 + cc];
        float av[4] = {a.x, a.y, a.z, a.w};
        float bv[4] = {b.x, b.y, b.z, b.w};
        #pragma unroll
        for (int j = 0; j < 4; ++j)
            #pragma unroll
            for (int i = 0; i < 4; ++i)
                acc[j][i] = fmaf(av[j], bv[i], acc[j][i]);
    }

    float h1v[4][4];
    #pragma unroll
    for (int j = 0; j < 4; ++j) {
        int e   = er + j;
        int qid = sQid[e], hd = sHead[e], tl = sTail[e];
        float4 qv = *(const float4*)&qc[qid * 64 + cc];
        float4 hv = *(const float4*)&nhp[hd * 64 + cc];
        float4 tv = *(const float4*)&ntp[tl * 64 + cc];
        float4 bv = *(const float4*)&sB1p[cc];
        h1v[j][0] = fmaxf(acc[j][0] + qv.x + hv.x + tv.x + bv.x, 0.f);
        h1v[j][1] = fmaxf(acc[j][1] + qv.y + hv.y + tv.y + bv.y, 0.f);
        h1v[j][2] = fmaxf(acc[j][2] + qv.z + hv.z + tv.z + bv.z, 0.f);
        h1v[j][3] = fmaxf(acc[j][3] + qv.w + hv.w + tv.w + bv.w, 0.f);
    }
    __syncthreads();   // all XT / Wr' reads done

    // H1 transposed into sBuf; W2 regs -> bank-phased panels (stride 2052 = 64*32+4)
    #pragma unroll
    for (int i = 0; i < 4; ++i) {
        *(float4*)&sBuf[(cc + i) * 68 + er] =
            make_float4(h1v[0][i], h1v[1][i], h1v[2][i], h1v[3][i]);
    }
    #pragma unroll
    for (int i = 0; i < 8; ++i) {
        int f = t + i * 256;
        int k = f >> 5, c = (f & 31) * 4;
        *(float4*)&sWU[(c >> 5) * 2052 + k * 32 + (c & 31)] = w2r[i];
    }
    __syncthreads();

    // ---- h2 = relu(H1 @ W2 + b2); logit = h2 @ Wh + bh ----
    const int cc2 = (t & 15) * 8;
    const int pb  = (cc2 >> 5) * 2052 + (cc2 & 31);
    float acc2[4][8];
    #pragma unroll
    for (int j = 0; j < 4; ++j)
        #pragma unroll
        for (int i = 0; i < 8; ++i) acc2[j][i] = 0.f;

    #pragma unroll 2
    for (int k = 0; k < 64; ++k) {
        float4 a  = *(const float4*)&sBuf[k * 68 + er];
        float4 b0 = *(const float4*)&sWU[pb + k * 32];
        float4 b1v = *(const float4*)&sWU[pb + k * 32 + 4];
        float av[4] = {a.x, a.y, a.z, a.w};
        float bv[8] = {b0.x, b0.y, b0.z, b0.w, b1v.x, b1v.y, b1v.z, b1v.w};
        #pragma unroll
        for (int j = 0; j < 4; ++j)
            #pragma unroll
            for (int i = 0; i < 8; ++i)
                acc2[j][i] = fmaf(av[j], bv[i], acc2[j][i]);
    }

    float part[4];
    #pragma unroll
    for (int j = 0; j < 4; ++j) {
        float s = 0.f;
        #pragma unroll
        for (int i = 0; i < 8; ++i) {
            float h2 = fmaxf(acc2[j][i] + sB2[cc2 + i], 0.f);
            s = fmaf(h2, sWh[cc2 + i], s);
        }
        part[j] = s;
    }
    #pragma unroll
    for (int m = 1; m < 16; m <<= 1) {
        part[0] += __shfl_xor(part[0], m, 64);
        part[1] += __shfl_xor(part[1], m, 64);
        part[2] += __shfl_xor(part[2], m, 64);
        part[3] += __shfl_xor(part[3], m, 64);
    }
    if ((t & 15) == 0) {
        float bb = bh[0];
        float4 o;
        o.x = 1.f / (1.f + __expf(-(part[0] + bb)));
        o.y = 1.f / (1.f + __expf(-(part[1] + bb)));
        o.z = 1.f / (1.f + __expf(-(part[2] + bb)));
        o.w = 1.f / (1.f + __expf(-(part[3] + bb)));
        *(float4*)&out[ebase + er] = o;
    }
}

extern "C" void kernel_launch(void* const* d_in, const int* in_sizes, int n_in,
                              void* d_out, int out_size, void* d_ws, size_t ws_size,
                              hipStream_t stream)
{
    const float* Q   = (const float*)d_in[0];
    const float* Xn  = (const float*)d_in[1];
    const float* Xe  = (const float*)d_in[2];
    const int*   EI  = (const int*)d_in[3];
    const int*   NB  = (const int*)d_in[4];
    const float* Wq  = (const float*)d_in[5];
    const float* bq  = (const float*)d_in[6];
    const float* We  = (const float*)d_in[7];
    const float* be  = (const float*)d_in[8];
    const float* Wr  = (const float*)d_in[9];
    const float* br  = (const float*)d_in[10];
    const float* W1  = (const float*)d_in[11];
    const float* b1  = (const float*)d_in[12];
    const float* W2  = (const float*)d_in[13];
    const float* b2  = (const float*)d_in[14];
    const float* Wh  = (const float*)d_in[15];
    const float* bh  = (const float*)d_in[16];
    float* out = (float*)d_out;
    float* ws  = (float*)d_ws;

    prep_kernel<<<NBN + 2, 256, 0, stream>>>(Q, Xn, Wq, bq, We, be, Wr, br, W1, b1, ws);
    edge_kernel<<<NEDGE / 64, 256, 0, stream>>>(Xe, EI, NB, W2, b2, Wh, bh, ws, out);
}

// Round 2
// 375.060 us; speedup vs baseline: 1.5379x; 1.5379x over previous
//
#include <hip/hip_runtime.h>

#define NNODE 50000
#define NEDGE 800000

typedef __attribute__((ext_vector_type(8))) short bf16x8;
typedef __attribute__((ext_vector_type(4))) float f32x4;

// workspace byte offsets
#define WB_QCB   0          // 64*64 bf16   qc + all folded biases
#define WB_WRTB  8192       // 64*64 bf16   (Wr@W1r)^T  [n][k]
#define WB_W2TB  16384      // 128*64 bf16  W2^T        [n][k]
#define WB_WEH   33024      // 64*64 fp32   We@W1h
#define WB_WET   49408      // 64*64 fp32   We@W1t
#define WB_NHB   65792      // 50000*64 bf16
#define WB_NTB   6465792    // 50000*64 bf16

__device__ inline ushort f2b(float x) {           // fp32 -> bf16 RNE
    uint u = __float_as_uint(x);
    return (ushort)((u + 0x7fffu + ((u >> 16) & 1u)) >> 16);
}
__device__ inline float bLo(uint u) { return __uint_as_float(u << 16); }
__device__ inline float bHi(uint u) { return __uint_as_float(u & 0xffff0000u); }

__device__ inline void stage64(float* dst, const float* __restrict__ src, int t) {
    #pragma unroll
    for (int i = 0; i < 4; ++i) {
        int f = t + i * 256;
        *(float4*)&dst[f * 4] = *(const float4*)&src[f * 4];
    }
}

// C[r0+j][c0+i] = sum_k A[r0+j][k]*B[k][c0+i]; A,B 64x64 row-major in LDS
__device__ inline void gemm64(const float* sA, const float* sB, int t, float acc[4][4]) {
    const int r0 = (t >> 4) * 4, c0 = (t & 15) * 4;
    #pragma unroll
    for (int j = 0; j < 4; ++j)
        #pragma unroll
        for (int i = 0; i < 4; ++i) acc[j][i] = 0.f;
    #pragma unroll 4
    for (int k = 0; k < 64; ++k) {
        float4 b = *(const float4*)&sB[k * 64 + c0];
        float bv[4] = {b.x, b.y, b.z, b.w};
        #pragma unroll
        for (int j = 0; j < 4; ++j) {
            float a = sA[(r0 + j) * 64 + k];
            #pragma unroll
            for (int i = 0; i < 4; ++i) acc[j][i] = fmaf(a, bv[i], acc[j][i]);
        }
    }
}

__global__ __launch_bounds__(256)
void prep_small(const float* __restrict__ Q,
                const float* __restrict__ Wq, const float* __restrict__ bq,
                const float* __restrict__ We, const float* __restrict__ be,
                const float* __restrict__ Wr, const float* __restrict__ br,
                const float* __restrict__ W1, const float* __restrict__ b1,
                const float* __restrict__ W2, char* __restrict__ wsb)
{
    __shared__ float sA[4096], sB[4096], sC[4096], sBias[64];
    const int t = threadIdx.x;
    const int bid = blockIdx.x;
    const int r0 = (t >> 4) * 4, c0 = (t & 15) * 4;

    if (bid == 0) {
        // Wqq = Wq@W1[0:64]; qc = Q@Wqq + (b1 + bq@W1q + be@(W1h+W1t) + br@W1r)
        stage64(sA, Wq, t); stage64(sB, W1, t);
        __syncthreads();
        float acc[4][4];
        gemm64(sA, sB, t, acc);
        #pragma unroll
        for (int j = 0; j < 4; ++j)
            *(float4*)&sC[(r0 + j) * 64 + c0] = make_float4(acc[j][0], acc[j][1], acc[j][2], acc[j][3]);
        if (t < 64) {
            float s = b1[t];
            for (int k = 0; k < 64; ++k) {
                s = fmaf(bq[k], W1[k * 64 + t], s);
                s = fmaf(be[k], W1[(64 + k) * 64 + t] + W1[(192 + k) * 64 + t], s);
                s = fmaf(br[k], W1[(128 + k) * 64 + t], s);
            }
            sBias[t] = s;
        }
        __syncthreads();
        stage64(sA, Q, t);
        __syncthreads();
        gemm64(sA, sC, t, acc);
        ushort* qcb = (ushort*)(wsb + WB_QCB);
        #pragma unroll
        for (int j = 0; j < 4; ++j) {
            ushort4 p;
            p.x = f2b(acc[j][0] + sBias[c0 + 0]);
            p.y = f2b(acc[j][1] + sBias[c0 + 1]);
            p.z = f2b(acc[j][2] + sBias[c0 + 2]);
            p.w = f2b(acc[j][3] + sBias[c0 + 3]);
            *(ushort4*)&qcb[(r0 + j) * 64 + c0] = p;
        }
    } else if (bid == 1 || bid == 2) {
        // Weh / Wet (fp32, consumed by prep_nodes)
        const float* w1seg = W1 + (bid == 1 ? 64 * 64 : 192 * 64);
        float* dst = (float*)(wsb + (bid == 1 ? WB_WEH : WB_WET));
        stage64(sA, We, t); stage64(sB, w1seg, t);
        __syncthreads();
        float acc[4][4];
        gemm64(sA, sB, t, acc);
        #pragma unroll
        for (int j = 0; j < 4; ++j)
            *(float4*)&dst[(r0 + j) * 64 + c0] = make_float4(acc[j][0], acc[j][1], acc[j][2], acc[j][3]);
    } else if (bid == 3) {
        // WrT = (Wr@W1r)^T, bf16
        stage64(sA, Wr, t); stage64(sB, W1 + 128 * 64, t);
        __syncthreads();
        float acc[4][4];
        gemm64(sA, sB, t, acc);
        ushort* wrtb = (ushort*)(wsb + WB_WRTB);
        #pragma unroll
        for (int j = 0; j < 4; ++j)
            #pragma unroll
            for (int i = 0; i < 4; ++i)
                wrtb[(c0 + i) * 64 + (r0 + j)] = f2b(acc[j][i]);
    } else {
        // W2^T bf16
        ushort* w2tb = (ushort*)(wsb + WB_W2TB);
        #pragma unroll
        for (int i = 0; i < 32; ++i) {
            int f = t + i * 256;           // f < 8192
            int k = f >> 7, n = f & 127;
            w2tb[n * 64 + k] = f2b(W2[f]);
        }
    }
}

__global__ __launch_bounds__(256)
void prep_nodes(const float* __restrict__ Xn, const char* __restrict__ wsb_c,
                char* __restrict__ wsb)
{
    __shared__ float sXT[64 * 68];
    __shared__ float sWeh[4096], sWet[4096];
    const int t = threadIdx.x;
    const int nbase = blockIdx.x * 64;
    const float* Weh = (const float*)(wsb_c + WB_WEH);
    const float* Wet = (const float*)(wsb_c + WB_WET);
    ushort* nhb = (ushort*)(wsb + WB_NHB);
    ushort* ntb = (ushort*)(wsb + WB_NTB);

    #pragma unroll
    for (int i = 0; i < 4; ++i) {
        int f = t + i * 256;
        int n = f >> 4, s4 = (f & 15) * 4;
        int gn = nbase + n;
        float4 v = make_float4(0.f, 0.f, 0.f, 0.f);
        if (gn < NNODE) v = *(const float4*)&Xn[gn * 64 + s4];
        sXT[(s4 + 0) * 68 + n] = v.x;
        sXT[(s4 + 1) * 68 + n] = v.y;
        sXT[(s4 + 2) * 68 + n] = v.z;
        sXT[(s4 + 3) * 68 + n] = v.w;
    }
    #pragma unroll
    for (int i = 0; i < 4; ++i) {
        int f = t + i * 256;
        *(float4*)&sWeh[f * 4] = *(const float4*)&Weh[f * 4];
        *(float4*)&sWet[f * 4] = *(const float4*)&Wet[f * 4];
    }
    __syncthreads();

    const int er = (t >> 4) * 4, cc = (t & 15) * 4;
    float ah[4][4], at[4][4];
    #pragma unroll
    for (int j = 0; j < 4; ++j)
        #pragma unroll
        for (int i = 0; i < 4; ++i) { ah[j][i] = 0.f; at[j][i] = 0.f; }
    #pragma unroll 4
    for (int k = 0; k < 64; ++k) {
        float4 a  = *(const float4*)&sXT[k * 68 + er];
        float4 bh = *(const float4*)&sWeh[k * 64 + cc];
        float4 bt = *(const float4*)&sWet[k * 64 + cc];
        float av[4] = {a.x, a.y, a.z, a.w};
        #pragma unroll
        for (int j = 0; j < 4; ++j) {
            ah[j][0] = fmaf(av[j], bh.x, ah[j][0]); ah[j][1] = fmaf(av[j], bh.y, ah[j][1]);
            ah[j][2] = fmaf(av[j], bh.z, ah[j][2]); ah[j][3] = fmaf(av[j], bh.w, ah[j][3]);
            at[j][0] = fmaf(av[j], bt.x, at[j][0]); at[j][1] = fmaf(av[j], bt.y, at[j][1]);
            at[j][2] = fmaf(av[j], bt.z, at[j][2]); at[j][3] = fmaf(av[j], bt.w, at[j][3]);
        }
    }
    #pragma unroll
    for (int j = 0; j < 4; ++j) {
        int n = nbase + er + j;
        if (n < NNODE) {
            ushort4 ph, pt;
            ph.x = f2b(ah[j][0]); ph.y = f2b(ah[j][1]); ph.z = f2b(ah[j][2]); ph.w = f2b(ah[j][3]);
            pt.x = f2b(at[j][0]); pt.y = f2b(at[j][1]); pt.z = f2b(at[j][2]); pt.w = f2b(at[j][3]);
            *(ushort4*)&nhb[n * 64 + cc] = ph;
            *(ushort4*)&ntb[n * 64 + cc] = pt;
        }
    }
}

__global__ __launch_bounds__(256, 3)
void edge_kernel(const float* __restrict__ Xe,
                 const int* __restrict__ EI,
                 const int* __restrict__ NB,
                 const float* __restrict__ b2,
                 const float* __restrict__ Wh,
                 const float* __restrict__ bh,
                 const char* __restrict__ wsb,
                 float* __restrict__ out)
{
    __shared__ ushort sX[64 * 72];     // X tile bf16; reused as H1 bf16
    __shared__ ushort sWr[64 * 72];    // Wr'^T bf16 rows n
    __shared__ ushort sW2[128 * 72];   // W2^T bf16 rows n
    __shared__ ushort sG[64 * 72];     // gathered additive term, bf16
    __shared__ float  sB2s[128], sWhs[128];

    const int t = threadIdx.x;
    const int ebase = blockIdx.x * 64;
    const ushort* qcb  = (const ushort*)(wsb + WB_QCB);
    const ushort* wrtb = (const ushort*)(wsb + WB_WRTB);
    const ushort* w2tb = (const ushort*)(wsb + WB_W2TB);
    const ushort* nhb  = (const ushort*)(wsb + WB_NHB);
    const ushort* ntb  = (const ushort*)(wsb + WB_NTB);

    // ---- gather chain (issue earliest: 3-deep dependent loads) ----
    const int eg = t >> 2;
    const int c0 = (t & 3) * 16;
    int hd = EI[ebase + eg];
    int tl = EI[NEDGE + ebase + eg];
    int qi = NB[hd];
    uint4 ga0 = *(const uint4*)&qcb[qi * 64 + c0];
    uint4 ga1 = *(const uint4*)&qcb[qi * 64 + c0 + 8];
    uint4 gb0 = *(const uint4*)&nhb[hd * 64 + c0];
    uint4 gb1 = *(const uint4*)&nhb[hd * 64 + c0 + 8];
    uint4 gc0 = *(const uint4*)&ntb[tl * 64 + c0];
    uint4 gc1 = *(const uint4*)&ntb[tl * 64 + c0 + 8];

    // ---- X tile + weight loads ----
    float4 xv[4];
    #pragma unroll
    for (int i = 0; i < 4; ++i) {
        int f = t + i * 256;
        xv[i] = *(const float4*)&Xe[(ebase + (f >> 4)) * 64 + (f & 15) * 4];
    }
    uint4 wrl[2], w2l[4];
    #pragma unroll
    for (int i = 0; i < 2; ++i) {
        int f = t + i * 256;
        wrl[i] = *(const uint4*)&wrtb[(f >> 3) * 64 + (f & 7) * 8];
    }
    #pragma unroll
    for (int i = 0; i < 4; ++i) {
        int f = t + i * 256;
        w2l[i] = *(const uint4*)&w2tb[(f >> 3) * 64 + (f & 7) * 8];
    }
    if (t < 128) { sB2s[t] = b2[t]; sWhs[t] = Wh[t]; }
    float bh0 = bh[0];

    // ---- sum gathers -> sG (bf16) ----
    {
        uint pk[8];
        const uint* ua = (const uint*)&ga0; const uint* ub = (const uint*)&gb0;
        const uint* uc = (const uint*)&gc0;
        #pragma unroll
        for (int j = 0; j < 4; ++j) {
            float lo = bLo(ua[j]) + bLo(ub[j]) + bLo(uc[j]);
            float hi = bHi(ua[j]) + bHi(ub[j]) + bHi(uc[j]);
            pk[j] = (uint)f2b(lo) | ((uint)f2b(hi) << 16);
        }
        ua = (const uint*)&ga1; ub = (const uint*)&gb1; uc = (const uint*)&gc1;
        #pragma unroll
        for (int j = 0; j < 4; ++j) {
            float lo = bLo(ua[j]) + bLo(ub[j]) + bLo(uc[j]);
            float hi = bHi(ua[j]) + bHi(ub[j]) + bHi(uc[j]);
            pk[4 + j] = (uint)f2b(lo) | ((uint)f2b(hi) << 16);
        }
        *(uint4*)&sG[eg * 72 + c0]     = make_uint4(pk[0], pk[1], pk[2], pk[3]);
        *(uint4*)&sG[eg * 72 + c0 + 8] = make_uint4(pk[4], pk[5], pk[6], pk[7]);
    }
    // ---- X -> bf16 LDS (row-major, stride 72) ----
    #pragma unroll
    for (int i = 0; i < 4; ++i) {
        int f = t + i * 256;
        int e = f >> 4, s4 = (f & 15) * 4;
        uint lo = (uint)f2b(xv[i].x) | ((uint)f2b(xv[i].y) << 16);
        uint hi = (uint)f2b(xv[i].z) | ((uint)f2b(xv[i].w) << 16);
        *(uint2*)&sX[e * 72 + s4] = make_uint2(lo, hi);
    }
    #pragma unroll
    for (int i = 0; i < 2; ++i) {
        int f = t + i * 256;
        *(uint4*)&sWr[(f >> 3) * 72 + (f & 7) * 8] = wrl[i];
    }
    #pragma unroll
    for (int i = 0; i < 4; ++i) {
        int f = t + i * 256;
        *(uint4*)&sW2[(f >> 3) * 72 + (f & 7) * 8] = w2l[i];
    }
    __syncthreads();

    const int lane = t & 63;
    const int w = t >> 6;          // M-tile for this wave
    const int m = lane & 15;
    const int qq = lane >> 4;
    const int q8 = qq * 8;

    // ---- h1 = relu(X@Wr' + g) via MFMA ----
    bf16x8 a0 = *(const bf16x8*)&sX[(w * 16 + m) * 72 + q8];
    bf16x8 a1 = *(const bf16x8*)&sX[(w * 16 + m) * 72 + 32 + q8];
    f32x4 acc1[4];
    #pragma unroll
    for (int nt = 0; nt < 4; ++nt) {
        bf16x8 b0 = *(const bf16x8*)&sWr[(nt * 16 + m) * 72 + q8];
        bf16x8 b1v = *(const bf16x8*)&sWr[(nt * 16 + m) * 72 + 32 + q8];
        f32x4 c = {0.f, 0.f, 0.f, 0.f};
        c = __builtin_amdgcn_mfma_f32_16x16x32_bf16(a0, b0, c, 0, 0, 0);
        c = __builtin_amdgcn_mfma_f32_16x16x32_bf16(a1, b1v, c, 0, 0, 0);
        acc1[nt] = c;
    }
    ushort h1s[4][4];
    #pragma unroll
    for (int nt = 0; nt < 4; ++nt) {
        int c = nt * 16 + m;
        #pragma unroll
        for (int r = 0; r < 4; ++r) {
            int e = w * 16 + qq * 4 + r;
            float gv = __uint_as_float(((uint)sG[e * 72 + c]) << 16);
            h1s[nt][r] = f2b(fmaxf(acc1[nt][r] + gv, 0.f));
        }
    }
    __syncthreads();
    #pragma unroll
    for (int nt = 0; nt < 4; ++nt) {
        int c = nt * 16 + m;
        #pragma unroll
        for (int r = 0; r < 4; ++r) {
            int e = w * 16 + qq * 4 + r;
            sX[e * 72 + c] = h1s[nt][r];
        }
    }
    __syncthreads();

    // ---- h2 = relu(H1@W2 + b2); logit = h2@Wh + bh ----
    bf16x8 A0 = *(const bf16x8*)&sX[(w * 16 + m) * 72 + q8];
    bf16x8 A1 = *(const bf16x8*)&sX[(w * 16 + m) * 72 + 32 + q8];
    float part[4] = {0.f, 0.f, 0.f, 0.f};
    #pragma unroll
    for (int nt = 0; nt < 8; ++nt) {
        bf16x8 B0 = *(const bf16x8*)&sW2[(nt * 16 + m) * 72 + q8];
        bf16x8 B1 = *(const bf16x8*)&sW2[(nt * 16 + m) * 72 + 32 + q8];
        f32x4 c = {0.f, 0.f, 0.f, 0.f};
        c = __builtin_amdgcn_mfma_f32_16x16x32_bf16(A0, B0, c, 0, 0, 0);
        c = __builtin_amdgcn_mfma_f32_16x16x32_bf16(A1, B1, c, 0, 0, 0);
        int col = nt * 16 + m;
        float b2v = sB2s[col], whv = sWhs[col];
        #pragma unroll
        for (int r = 0; r < 4; ++r)
            part[r] = fmaf(fmaxf(c[r] + b2v, 0.f), whv, part[r]);
    }
    #pragma unroll
    for (int md = 1; md < 16; md <<= 1) {
        part[0] += __shfl_xor(part[0], md, 64);
        part[1] += __shfl_xor(part[1], md, 64);
        part[2] += __shfl_xor(part[2], md, 64);
        part[3] += __shfl_xor(part[3], md, 64);
    }
    if (m == 0) {
        float4 o;
        o.x = 1.f / (1.f + __expf(-(part[0] + bh0)));
        o.y = 1.f / (1.f + __expf(-(part[1] + bh0)));
        o.z = 1.f / (1.f + __expf(-(part[2] + bh0)));
        o.w = 1.f / (1.f + __expf(-(part[3] + bh0)));
        *(float4*)&out[ebase + w * 16 + qq * 4] = o;
    }
}

extern "C" void kernel_launch(void* const* d_in, const int* in_sizes, int n_in,
                              void* d_out, int out_size, void* d_ws, size_t ws_size,
                              hipStream_t stream)
{
    const float* Q   = (const float*)d_in[0];
    const float* Xn  = (const float*)d_in[1];
    const float* Xe  = (const float*)d_in[2];
    const int*   EI  = (const int*)d_in[3];
    const int*   NB  = (const int*)d_in[4];
    const float* Wq  = (const float*)d_in[5];
    const float* bq  = (const float*)d_in[6];
    const float* We  = (const float*)d_in[7];
    const float* be  = (const float*)d_in[8];
    const float* Wr  = (const float*)d_in[9];
    const float* br  = (const float*)d_in[10];
    const float* W1  = (const float*)d_in[11];
    const float* b1  = (const float*)d_in[12];
    const float* W2  = (const float*)d_in[13];
    const float* b2  = (const float*)d_in[14];
    const float* Wh  = (const float*)d_in[15];
    const float* bh  = (const float*)d_in[16];
    float* out = (float*)d_out;
    char*  wsb = (char*)d_ws;

    prep_small<<<5, 256, 0, stream>>>(Q, Wq, bq, We, be, Wr, br, W1, b1, W2, wsb);
    prep_nodes<<<(NNODE + 63) / 64, 256, 0, stream>>>(Xn, wsb, wsb);
    edge_kernel<<<NEDGE / 64, 256, 0, stream>>>(Xe, EI, NB, b2, Wh, bh, wsb, out);
}